// Round 1
// baseline (167.547 us; speedup 1.0000x reference)
//
#include <hip/hip_runtime.h>

// RuleBasedEmbedding: out[t][e] = sum_d base_emb[token_ids[t]][d] * rule_transform[token_rules[token_ids[t]]][d][e]
// B*S = 8192 tokens, D = 256, 100 rules.
//
// Round 1 baseline: one wave (64 lanes) per token; each lane owns 4 output
// columns (float4). M rows read coalesced as float4 (1 KB per wave-instr).
// Base embedding staged in LDS, read as wave-uniform broadcast (conflict-free).

#define DIM 256
#define TOKENS_PER_BLOCK 4   // 4 waves of 64

__global__ __launch_bounds__(256, 4)
void rule_embed_kernel(const int* __restrict__ token_ids,
                       const float* __restrict__ base_emb,
                       const float* __restrict__ rule_mats,
                       const int* __restrict__ token_rules,
                       float* __restrict__ out,
                       int n_tokens) {
    const int wave = threadIdx.x >> 6;                    // 0..3
    const int lane = threadIdx.x & 63;                    // 0..63
    const int tok  = blockIdx.x * TOKENS_PER_BLOCK + wave;

    __shared__ float base[TOKENS_PER_BLOCK][DIM];

    if (tok < n_tokens) {
        const int tid = token_ids[tok];
        // stage base embedding: 64 lanes x float4 = 256 floats
        const float4 bv = reinterpret_cast<const float4*>(base_emb + (size_t)tid * DIM)[lane];
        reinterpret_cast<float4*>(base[wave])[lane] = bv;
    }
    __syncthreads();

    if (tok >= n_tokens) return;

    const int tid = token_ids[tok];
    const int r   = token_rules[tid];
    const float4* __restrict__ M4 =
        reinterpret_cast<const float4*>(rule_mats + (size_t)r * DIM * DIM);

    float4 acc = make_float4(0.f, 0.f, 0.f, 0.f);

    // out[tok][lane*4 .. lane*4+3] = sum_d base[d] * M[d][lane*4 ..]
    #pragma unroll 8
    for (int d = 0; d < DIM; ++d) {
        const float  b = base[wave][d];           // LDS broadcast (same addr all lanes)
        const float4 m = M4[d * (DIM / 4) + lane]; // coalesced 16B/lane
        acc.x += b * m.x;
        acc.y += b * m.y;
        acc.z += b * m.z;
        acc.w += b * m.w;
    }

    reinterpret_cast<float4*>(out + (size_t)tok * DIM)[lane] = acc;
}

extern "C" void kernel_launch(void* const* d_in, const int* in_sizes, int n_in,
                              void* d_out, int out_size, void* d_ws, size_t ws_size,
                              hipStream_t stream) {
    const int*   token_ids   = (const int*)d_in[0];    // [4, 2048]
    const float* base_emb    = (const float*)d_in[1];  // [32000, 256]
    const float* rule_mats   = (const float*)d_in[2];  // [100, 256, 256]
    const int*   token_rules = (const int*)d_in[3];    // [32000]
    float*       out         = (float*)d_out;          // [4, 2048, 256]

    const int n_tokens = in_sizes[0];                  // 8192
    const int blocks = (n_tokens + TOKENS_PER_BLOCK - 1) / TOKENS_PER_BLOCK;

    rule_embed_kernel<<<blocks, 256, 0, stream>>>(
        token_ids, base_emb, rule_mats, token_rules, out, n_tokens);
}

// Round 3
// 76.289 us; speedup vs baseline: 2.1962x; 2.1962x over previous
//
#include <hip/hip_runtime.h>

// RuleBasedEmbedding round 3: rule-sorted token chunks + XCD-resident rule matrices.
// Round-2 bug fixed: base embedding gather must go through token_ids[] (the
// sort list stores token POSITIONS; embeddings are indexed by token ID).
//
// out[t][e] = sum_d base[token_ids[t]][d] * M[rule[token_ids[t]]][d][e]
// 8192 tokens, D=256, 100 rules.
//
// Pipeline (all on `stream`, ws-backed):
//   A init_ws    : zero counters, fill list/perm/chunk_rule with -1
//   B count      : histogram tokens per rule
//   C plan       : prefix sums, chunk->rule map, per-XCD chunk permutation
//   D scatter    : counting-sort token positions into rule-grouped list
//   E compute    : chunk = 8 same-rule tokens; 2 col-half waves/chunk;
//                  blockIdx&7 pins each rule class to one XCD -> M is L2-resident.

#define NTOK   8192
#define NRULE  100
#define DIM    256
#define T      8                      // tokens per chunk (register tile)
#define MAXCH  1152                   // >= 8192/T + NRULE = 1124 (worst-case chunks)
#define LIST_SZ (NTOK + NRULE * T)    // 8992 padded token slots

// ws int layout
#define WS_COUNTS 0
#define WS_CURSOR 128
#define WS_CHRULE 256
#define WS_LIST   (WS_CHRULE + MAXCH)            // 1408
#define WS_PERM   (WS_LIST + LIST_SZ)            // 10400
#define WS_TOTAL  (WS_PERM + 8 * MAXCH)          // 19616 ints = 78464 B

// ---------------- A: init workspace ----------------
__global__ void init_ws_kernel(int* ws) {
    for (int i = blockIdx.x * blockDim.x + threadIdx.x; i < WS_TOTAL;
         i += gridDim.x * blockDim.x)
        ws[i] = (i < WS_CHRULE) ? 0 : -1;
}

// ---------------- B: count tokens per rule ----------------
__global__ void count_kernel(const int* __restrict__ token_ids,
                             const int* __restrict__ token_rules, int* ws) {
    int t = blockIdx.x * blockDim.x + threadIdx.x;
    if (t < NTOK) {
        int r = token_rules[token_ids[t]];
        atomicAdd(&ws[WS_COUNTS + r], 1);
    }
}

// ---------------- C: plan (single block) ----------------
__global__ void plan_kernel(int* ws) {
    __shared__ int s_cnt[NRULE];
    __shared__ int s_choff[NRULE + 1];   // chunk-index prefix
    __shared__ int s_poff[NRULE + 1];    // padded element prefix (= choff*T)
    __shared__ int s_xbase[NRULE];       // base slot within rule's XCD list
    const int tid = threadIdx.x;
    if (tid < NRULE) s_cnt[tid] = ws[WS_COUNTS + tid];
    __syncthreads();
    if (tid == 0) {
        int po = 0, co = 0;
        int xc[8] = {0, 0, 0, 0, 0, 0, 0, 0};
        for (int r = 0; r < NRULE; ++r) {
            s_poff[r] = po; s_choff[r] = co;
            int nch = (s_cnt[r] + T - 1) / T;
            s_xbase[r] = xc[r & 7];
            xc[r & 7] += nch;
            po += nch * T; co += nch;
        }
        s_poff[NRULE] = po; s_choff[NRULE] = co;
    }
    __syncthreads();
    if (tid < NRULE) ws[WS_CURSOR + tid] = s_poff[tid];
    const int tc = s_choff[NRULE];
    for (int c = tid; c < tc; c += blockDim.x) {
        int lo = 0, hi = NRULE - 1;            // largest r with choff[r] <= c
        while (lo < hi) {
            int mid = (lo + hi + 1) >> 1;
            if (s_choff[mid] <= c) lo = mid; else hi = mid - 1;
        }
        ws[WS_CHRULE + c] = lo;
        ws[WS_PERM + (lo & 7) * MAXCH + s_xbase[lo] + (c - s_choff[lo])] = c;
    }
}

// ---------------- D: scatter token positions ----------------
__global__ void scatter_kernel(const int* __restrict__ token_ids,
                               const int* __restrict__ token_rules, int* ws) {
    int t = blockIdx.x * blockDim.x + threadIdx.x;
    if (t < NTOK) {
        int r = token_rules[token_ids[t]];
        int pos = atomicAdd(&ws[WS_CURSOR + r], 1);
        ws[WS_LIST + pos] = t;
    }
}

// ---------------- E: main compute ----------------
// block = 256 threads = 4 waves = 2 chunks x 2 col-halves. LDS stages base embeds.
__global__ __launch_bounds__(256)
void compute_kernel(const int* __restrict__ token_ids,
                    const float* __restrict__ base_emb,
                    const float* __restrict__ rule_mats,
                    const int* __restrict__ ws,
                    float* __restrict__ out) {
    const int xcd  = blockIdx.x & 7;
    const int pair = blockIdx.x >> 3;
    const int c0 = ws[WS_PERM + xcd * MAXCH + pair * 2 + 0];
    const int c1 = ws[WS_PERM + xcd * MAXCH + pair * 2 + 1];
    if (c0 < 0 && c1 < 0) return;                       // block-uniform

    __shared__ float sb[2][T][DIM];                     // 16 KB
    __shared__ int   stk[2][T];                         // token POSITIONS (for out)
    __shared__ int   sid[2][T];                         // token IDS (for base_emb)
    const int tid = threadIdx.x;

    if (tid < 2 * T) {
        int lc = tid >> 3, i = tid & 7;
        int c = lc ? c1 : c0;
        int tk = (c >= 0) ? ws[WS_LIST + c * T + i] : -1;
        stk[lc][i] = tk;
        sid[lc][i] = (tk >= 0) ? token_ids[tk] : -1;
    }
    __syncthreads();

    // stage base embeddings: 2*8 tokens x 64 float4 (gather by token ID)
    for (int s = tid; s < 2 * T * (DIM / 4); s += 256) {
        int lc = s >> 9, t = (s >> 6) & (T - 1), d4 = s & 63;
        int id = sid[lc][t];
        float4 v = make_float4(0.f, 0.f, 0.f, 0.f);
        if (id >= 0)
            v = reinterpret_cast<const float4*>(base_emb + (size_t)id * DIM)[d4];
        reinterpret_cast<float4*>(&sb[lc][t][0])[d4] = v;
    }
    __syncthreads();

    const int wave = tid >> 6, lane = tid & 63;
    const int lc = wave >> 1, h = wave & 1;
    const int c = lc ? c1 : c0;
    if (c < 0) return;
    const int r = ws[WS_CHRULE + c];

    const float* Mp = rule_mats + (size_t)r * DIM * DIM + h * 128 + lane * 2;
    float2 acc[T];
    #pragma unroll
    for (int t = 0; t < T; ++t) acc[t] = make_float2(0.f, 0.f);

    for (int d = 0; d < DIM; d += 4) {
        const float2 m0 = *reinterpret_cast<const float2*>(Mp + (size_t)(d + 0) * DIM);
        const float2 m1 = *reinterpret_cast<const float2*>(Mp + (size_t)(d + 1) * DIM);
        const float2 m2 = *reinterpret_cast<const float2*>(Mp + (size_t)(d + 2) * DIM);
        const float2 m3 = *reinterpret_cast<const float2*>(Mp + (size_t)(d + 3) * DIM);
        #pragma unroll
        for (int t = 0; t < T; ++t) {
            const float4 b = *reinterpret_cast<const float4*>(&sb[lc][t][d]); // LDS broadcast
            acc[t].x += b.x * m0.x + b.y * m1.x + b.z * m2.x + b.w * m3.x;
            acc[t].y += b.x * m0.y + b.y * m1.y + b.z * m2.y + b.w * m3.y;
        }
    }

    #pragma unroll
    for (int t = 0; t < T; ++t) {
        int tk = stk[lc][t];
        if (tk >= 0)
            *reinterpret_cast<float2*>(out + (size_t)tk * DIM + h * 128 + lane * 2) = acc[t];
    }
}

// ---------------- fallback (round-1 kernel) if ws too small ----------------
__global__ __launch_bounds__(256, 4)
void rule_embed_fallback(const int* __restrict__ token_ids,
                         const float* __restrict__ base_emb,
                         const float* __restrict__ rule_mats,
                         const int* __restrict__ token_rules,
                         float* __restrict__ out, int n_tokens) {
    const int wave = threadIdx.x >> 6, lane = threadIdx.x & 63;
    const int tok = blockIdx.x * 4 + wave;
    __shared__ float base[4][DIM];
    if (tok < n_tokens) {
        const int tid = token_ids[tok];
        reinterpret_cast<float4*>(base[wave])[lane] =
            reinterpret_cast<const float4*>(base_emb + (size_t)tid * DIM)[lane];
    }
    __syncthreads();
    if (tok >= n_tokens) return;
    const int tid = token_ids[tok];
    const int r = token_rules[tid];
    const float4* M4 = reinterpret_cast<const float4*>(rule_mats + (size_t)r * DIM * DIM);
    float4 acc = make_float4(0.f, 0.f, 0.f, 0.f);
    #pragma unroll 8
    for (int d = 0; d < DIM; ++d) {
        const float b = base[wave][d];
        const float4 m = M4[d * (DIM / 4) + lane];
        acc.x += b * m.x; acc.y += b * m.y; acc.z += b * m.z; acc.w += b * m.w;
    }
    reinterpret_cast<float4*>(out + (size_t)tok * DIM)[lane] = acc;
}

extern "C" void kernel_launch(void* const* d_in, const int* in_sizes, int n_in,
                              void* d_out, int out_size, void* d_ws, size_t ws_size,
                              hipStream_t stream) {
    const int*   token_ids   = (const int*)d_in[0];    // [4, 2048]
    const float* base_emb    = (const float*)d_in[1];  // [32000, 256]
    const float* rule_mats   = (const float*)d_in[2];  // [100, 256, 256]
    const int*   token_rules = (const int*)d_in[3];    // [32000]
    float*       out         = (float*)d_out;          // [4, 2048, 256]
    int*         ws          = (int*)d_ws;

    if (ws_size < (size_t)WS_TOTAL * sizeof(int)) {
        rule_embed_fallback<<<(NTOK + 3) / 4, 256, 0, stream>>>(
            token_ids, base_emb, rule_mats, token_rules, out, NTOK);
        return;
    }

    init_ws_kernel<<<32, 256, 0, stream>>>(ws);
    count_kernel<<<NTOK / 256, 256, 0, stream>>>(token_ids, token_rules, ws);
    plan_kernel<<<1, 256, 0, stream>>>(ws);
    scatter_kernel<<<NTOK / 256, 256, 0, stream>>>(token_ids, token_rules, ws);
    compute_kernel<<<8 * (MAXCH / 2), 256, 0, stream>>>(token_ids, base_emb, rule_mats, ws, out);
}

// Round 4
// 72.338 us; speedup vs baseline: 2.3162x; 1.0546x over previous
//
#include <hip/hip_runtime.h>

// RuleBasedEmbedding round 4: rule-sorted chunks + XCD-resident matrices
// + latency attack: 4 waves/chunk (2 col-halves x 2 d-halves, LDS-reduced)
// and explicit double-buffered M-row prefetch in the d-loop.
//
// out[t][e] = sum_d base[token_ids[t]][d] * M[rule[token_ids[t]]][d][e]
// 8192 tokens, D=256, 100 rules.

#define NTOK   8192
#define NRULE  100
#define DIM    256
#define T      8                      // tokens per chunk (register tile)
#define MAXCH  1152                   // >= 8192/T + NRULE = 1124 (worst-case chunks)
#define LIST_SZ (NTOK + NRULE * T)    // 8992 padded token slots

// ws int layout
#define WS_COUNTS 0
#define WS_CURSOR 128
#define WS_CHRULE 256
#define WS_LIST   (WS_CHRULE + MAXCH)            // 1408
#define WS_PERM   (WS_LIST + LIST_SZ)            // 10400
#define WS_TOTAL  (WS_PERM + 8 * MAXCH)          // 19616 ints = 78464 B

// ---------------- A: init workspace ----------------
__global__ void init_ws_kernel(int* ws) {
    for (int i = blockIdx.x * blockDim.x + threadIdx.x; i < WS_TOTAL;
         i += gridDim.x * blockDim.x)
        ws[i] = (i < WS_CHRULE) ? 0 : -1;
}

// ---------------- B: count tokens per rule ----------------
__global__ void count_kernel(const int* __restrict__ token_ids,
                             const int* __restrict__ token_rules, int* ws) {
    int t = blockIdx.x * blockDim.x + threadIdx.x;
    if (t < NTOK) {
        int r = token_rules[token_ids[t]];
        atomicAdd(&ws[WS_COUNTS + r], 1);
    }
}

// ---------------- C: plan (single block) ----------------
__global__ void plan_kernel(int* ws) {
    __shared__ int s_cnt[NRULE];
    __shared__ int s_choff[NRULE + 1];   // chunk-index prefix
    __shared__ int s_poff[NRULE + 1];    // padded element prefix
    __shared__ int s_xbase[NRULE];       // base slot within rule's XCD list
    const int tid = threadIdx.x;
    if (tid < NRULE) s_cnt[tid] = ws[WS_COUNTS + tid];
    __syncthreads();
    if (tid == 0) {
        int po = 0, co = 0;
        int xc[8] = {0, 0, 0, 0, 0, 0, 0, 0};
        for (int r = 0; r < NRULE; ++r) {
            s_poff[r] = po; s_choff[r] = co;
            int nch = (s_cnt[r] + T - 1) / T;
            s_xbase[r] = xc[r & 7];
            xc[r & 7] += nch;
            po += nch * T; co += nch;
        }
        s_poff[NRULE] = po; s_choff[NRULE] = co;
    }
    __syncthreads();
    if (tid < NRULE) ws[WS_CURSOR + tid] = s_poff[tid];
    const int tc = s_choff[NRULE];
    for (int c = tid; c < tc; c += blockDim.x) {
        int lo = 0, hi = NRULE - 1;            // largest r with choff[r] <= c
        while (lo < hi) {
            int mid = (lo + hi + 1) >> 1;
            if (s_choff[mid] <= c) lo = mid; else hi = mid - 1;
        }
        ws[WS_CHRULE + c] = lo;
        ws[WS_PERM + (lo & 7) * MAXCH + s_xbase[lo] + (c - s_choff[lo])] = c;
    }
}

// ---------------- D: scatter token positions ----------------
__global__ void scatter_kernel(const int* __restrict__ token_ids,
                               const int* __restrict__ token_rules, int* ws) {
    int t = blockIdx.x * blockDim.x + threadIdx.x;
    if (t < NTOK) {
        int r = token_rules[token_ids[t]];
        int pos = atomicAdd(&ws[WS_CURSOR + r], 1);
        ws[WS_LIST + pos] = t;
    }
}

// ---------------- E: main compute ----------------
// One chunk per block. 4 waves = (col-half h) x (d-half dh); each wave does a
// 128x128 sub-matvec for 8 tokens with double-buffered M-row prefetch.
// dh=1 partials land in LDS; dh=0 waves combine and store.
__global__ __launch_bounds__(256)
void compute_kernel(const int* __restrict__ token_ids,
                    const float* __restrict__ base_emb,
                    const float* __restrict__ rule_mats,
                    const int* __restrict__ ws,
                    float* __restrict__ out) {
    const int xcd  = blockIdx.x & 7;
    const int slot = blockIdx.x >> 3;
    const int c = ws[WS_PERM + xcd * MAXCH + slot];
    if (c < 0) return;                                  // block-uniform

    __shared__ float sb[T][DIM];                        // 8 KB base embeds
    __shared__ float red[T][DIM];                       // 8 KB d-half partials
    __shared__ int   stk[T];                            // token positions
    __shared__ int   sid[T];                            // token ids
    const int tid = threadIdx.x;

    if (tid < T) {
        int tk = ws[WS_LIST + c * T + tid];
        stk[tid] = tk;
        sid[tid] = (tk >= 0) ? token_ids[tk] : -1;
    }
    __syncthreads();

    // stage base embeddings: 8 tokens x 64 float4 (gather by token ID)
    for (int s = tid; s < T * (DIM / 4); s += 256) {
        int t = s >> 6, d4 = s & 63;
        int id = sid[t];
        float4 v = make_float4(0.f, 0.f, 0.f, 0.f);
        if (id >= 0)
            v = reinterpret_cast<const float4*>(base_emb + (size_t)id * DIM)[d4];
        reinterpret_cast<float4*>(&sb[t][0])[d4] = v;
    }
    __syncthreads();

    const int wave = tid >> 6, lane = tid & 63;
    const int h  = wave & 1;        // column half: cols [h*128, h*128+128)
    const int dh = wave >> 1;       // d half: rows  [dh*128, dh*128+128)
    const int r  = ws[WS_CHRULE + c];

    const float* Mp = rule_mats + (size_t)r * DIM * DIM
                    + (size_t)(dh * 128) * DIM + h * 128 + lane * 2;

    float2 acc[T];
    #pragma unroll
    for (int t = 0; t < T; ++t) acc[t] = make_float2(0.f, 0.f);

    // double-buffered 4-row groups: prefetch next group while FMAing current
    float2 m0 = *reinterpret_cast<const float2*>(Mp + 0 * DIM);
    float2 m1 = *reinterpret_cast<const float2*>(Mp + 1 * DIM);
    float2 m2 = *reinterpret_cast<const float2*>(Mp + 2 * DIM);
    float2 m3 = *reinterpret_cast<const float2*>(Mp + 3 * DIM);

    for (int d = 0; d < 128; d += 4) {
        float2 n0, n1, n2, n3;
        const bool more = (d + 4) < 128;
        if (more) {
            n0 = *reinterpret_cast<const float2*>(Mp + (size_t)(d + 4) * DIM);
            n1 = *reinterpret_cast<const float2*>(Mp + (size_t)(d + 5) * DIM);
            n2 = *reinterpret_cast<const float2*>(Mp + (size_t)(d + 6) * DIM);
            n3 = *reinterpret_cast<const float2*>(Mp + (size_t)(d + 7) * DIM);
        }
        #pragma unroll
        for (int t = 0; t < T; ++t) {
            const float4 b = *reinterpret_cast<const float4*>(&sb[t][dh * 128 + d]);
            acc[t].x += b.x * m0.x + b.y * m1.x + b.z * m2.x + b.w * m3.x;
            acc[t].y += b.x * m0.y + b.y * m1.y + b.z * m2.y + b.w * m3.y;
        }
        if (more) { m0 = n0; m1 = n1; m2 = n2; m3 = n3; }
    }

    // combine d-halves via LDS
    if (dh == 1) {
        #pragma unroll
        for (int t = 0; t < T; ++t)
            *reinterpret_cast<float2*>(&red[t][h * 128 + lane * 2]) = acc[t];
    }
    __syncthreads();
    if (dh == 0) {
        #pragma unroll
        for (int t = 0; t < T; ++t) {
            const float2 o = *reinterpret_cast<const float2*>(&red[t][h * 128 + lane * 2]);
            acc[t].x += o.x; acc[t].y += o.y;
            int tk = stk[t];
            if (tk >= 0)
                *reinterpret_cast<float2*>(out + (size_t)tk * DIM + h * 128 + lane * 2) = acc[t];
        }
    }
}

// ---------------- fallback (round-1 kernel) if ws too small ----------------
__global__ __launch_bounds__(256, 4)
void rule_embed_fallback(const int* __restrict__ token_ids,
                         const float* __restrict__ base_emb,
                         const float* __restrict__ rule_mats,
                         const int* __restrict__ token_rules,
                         float* __restrict__ out, int n_tokens) {
    const int wave = threadIdx.x >> 6, lane = threadIdx.x & 63;
    const int tok = blockIdx.x * 4 + wave;
    __shared__ float base[4][DIM];
    if (tok < n_tokens) {
        const int tid = token_ids[tok];
        reinterpret_cast<float4*>(base[wave])[lane] =
            reinterpret_cast<const float4*>(base_emb + (size_t)tid * DIM)[lane];
    }
    __syncthreads();
    if (tok >= n_tokens) return;
    const int tid = token_ids[tok];
    const int r = token_rules[tid];
    const float4* M4 = reinterpret_cast<const float4*>(rule_mats + (size_t)r * DIM * DIM);
    float4 acc = make_float4(0.f, 0.f, 0.f, 0.f);
    #pragma unroll 8
    for (int d = 0; d < DIM; ++d) {
        const float b = base[wave][d];
        const float4 m = M4[d * (DIM / 4) + lane];
        acc.x += b * m.x; acc.y += b * m.y; acc.z += b * m.z; acc.w += b * m.w;
    }
    reinterpret_cast<float4*>(out + (size_t)tok * DIM)[lane] = acc;
}

extern "C" void kernel_launch(void* const* d_in, const int* in_sizes, int n_in,
                              void* d_out, int out_size, void* d_ws, size_t ws_size,
                              hipStream_t stream) {
    const int*   token_ids   = (const int*)d_in[0];    // [4, 2048]
    const float* base_emb    = (const float*)d_in[1];  // [32000, 256]
    const float* rule_mats   = (const float*)d_in[2];  // [100, 256, 256]
    const int*   token_rules = (const int*)d_in[3];    // [32000]
    float*       out         = (float*)d_out;          // [4, 2048, 256]
    int*         ws          = (int*)d_ws;

    if (ws_size < (size_t)WS_TOTAL * sizeof(int)) {
        rule_embed_fallback<<<(NTOK + 3) / 4, 256, 0, stream>>>(
            token_ids, base_emb, rule_mats, token_rules, out, NTOK);
        return;
    }

    init_ws_kernel<<<32, 256, 0, stream>>>(ws);
    count_kernel<<<NTOK / 256, 256, 0, stream>>>(token_ids, token_rules, ws);
    plan_kernel<<<1, 256, 0, stream>>>(ws);
    scatter_kernel<<<NTOK / 256, 256, 0, stream>>>(token_ids, token_rules, ws);
    compute_kernel<<<8 * MAXCH, 256, 0, stream>>>(token_ids, base_emb, rule_mats, ws, out);
}